// Round 4
// baseline (306.483 us; speedup 1.0000x reference)
//
#include <hip/hip_runtime.h>
#include <hip/hip_bf16.h>

// B=4, T=4096, C=1024, H=64 causal attention w/ RPE bias.
// Round 4: (a) flash_part is now BARRIER-FREE: K/V fragments load directly
// global->VGPR (fragment pattern is already a coalesced 16-row x 16B access,
// served from L2); LDS only for the wave-local P transpose. (b) proj_part
// gets #pragma unroll 1 to prevent full-unroll load hoisting -> VGPR spills
// (suspected cause of ~150us), plus ks staggering across blocks.

#define T_DIM 4096
#define C_DIM 1024
#define QT    64
#define KT    64
#define CK    512

typedef __attribute__((ext_vector_type(8))) short s16x8;
typedef __attribute__((ext_vector_type(4))) float f32x4;
typedef __attribute__((ext_vector_type(2))) unsigned int u32x2;

__device__ __forceinline__ short f2bf(float f) {
    unsigned u = __builtin_bit_cast(unsigned, f);
    u += 0x7FFFu + ((u >> 16) & 1u);
    return (short)(u >> 16);
}
__device__ __forceinline__ unsigned pack2(float a, float b) {
    unsigned ua = __builtin_bit_cast(unsigned, a);
    unsigned ub = __builtin_bit_cast(unsigned, b);
    ua += 0x7FFFu + ((ua >> 16) & 1u);
    ub += 0x7FFFu + ((ub >> 16) & 1u);
    return __builtin_amdgcn_perm(ub, ua, 0x07060302u);
}
__device__ __forceinline__ float bf2f(short s) {
    unsigned u = ((unsigned)(unsigned short)s) << 16;
    return __builtin_bit_cast(float, u);
}

// ---------------------------------------------------------------------------
// Kernel 1: weights -> B-fragment order: wfrag[ksAll][mat][nt][lane][8] bf16.
// w_q scaled by 0.125. grid (32, 3) x 256.
// ---------------------------------------------------------------------------
__global__ __launch_bounds__(256) void prep_frag(
    const float* __restrict__ wk, const float* __restrict__ wq,
    const float* __restrict__ wv, short* __restrict__ wfrag)
{
    int ksAll = blockIdx.x, mat = blockIdx.y;
    const float* w = (mat == 0) ? wk : ((mat == 1) ? wq : wv);
    float sc = (mat == 1) ? 0.125f : 1.0f;
    int nt = threadIdx.x >> 6, lane = threadIdx.x & 63;
    int quad = lane >> 4, l15 = lane & 15;
    int h = nt * 16 + l15;
    int cb = ksAll * 32 + quad * 8;
    s16x8 v;
    #pragma unroll
    for (int j = 0; j < 8; ++j) v[j] = f2bf(w[(cb + j) * 64 + h] * sc);
    *(s16x8*)&wfrag[((ksAll * 12 + mat * 4 + nt) * 64 + lane) * 8] = v;
}

// ---------------------------------------------------------------------------
// Kernel 2: streaming projection partials, no LDS / no barriers.
// grid (256, 4) x 256 thr = 4096 waves = 16/CU. pp[cq][row][mat*64+h] bf16.
// unroll 1: keep <=1 iteration's loads live (12 frag + 2 x) -> no spills.
// ---------------------------------------------------------------------------
__global__ __launch_bounds__(256) void proj_part(
    const float* __restrict__ x, const short* __restrict__ wfrag,
    short* __restrict__ pp)
{
    int w = threadIdx.x >> 6, lane = threadIdx.x & 63;
    int l15 = lane & 15, quad = lane >> 4;
    int row0 = (blockIdx.x * 4 + w) * 16;
    int cq = blockIdx.y;

    f32x4 acc[12];
    #pragma unroll
    for (int i = 0; i < 12; ++i) acc[i] = (f32x4){0.f, 0.f, 0.f, 0.f};

    const float* xrow = x + (size_t)(row0 + l15) * C_DIM + cq * 256;

    #pragma unroll 1
    for (int ksi = 0; ksi < 8; ++ksi) {
        int ks = (ksi + blockIdx.x) & 7;         // stagger L2 access across blocks
        int ksAll = cq * 8 + ks;
        const s16x8* fb = (const s16x8*)&wfrag[(size_t)(ksAll * 12 * 64 + lane) * 8];
        f32x4 x0 = *(const f32x4*)(xrow + ks * 32 + quad * 8);
        f32x4 x1 = *(const f32x4*)(xrow + ks * 32 + quad * 8 + 4);
        s16x8 af;
        unsigned p0 = pack2(x0[0], x0[1]), p1 = pack2(x0[2], x0[3]);
        unsigned p2 = pack2(x1[0], x1[1]), p3 = pack2(x1[2], x1[3]);
        af[0] = (short)p0; af[1] = (short)(p0 >> 16);
        af[2] = (short)p1; af[3] = (short)(p1 >> 16);
        af[4] = (short)p2; af[5] = (short)(p2 >> 16);
        af[6] = (short)p3; af[7] = (short)(p3 >> 16);
        #pragma unroll
        for (int f = 0; f < 12; ++f) {
            s16x8 bf = fb[f * 64];
            acc[f] = __builtin_amdgcn_mfma_f32_16x16x32_bf16(af, bf, acc[f], 0, 0, 0);
        }
    }
    short* base = pp + (size_t)cq * 16384 * 192;
    #pragma unroll
    for (int f = 0; f < 12; ++f) {
        int mat = f >> 2, nt = f & 3;
        #pragma unroll
        for (int r = 0; r < 4; ++r)
            base[(size_t)(row0 + quad * 4 + r) * 192 + mat * 64 + nt * 16 + l15] =
                f2bf(acc[f][r]);
    }
}

// ---------------------------------------------------------------------------
// Kernel 3: combine 4 partials -> kb, qb bf16 + transposed vtb (B,64,T).
// ---------------------------------------------------------------------------
__global__ __launch_bounds__(256) void proj_combine(
    const short* __restrict__ pp, short* __restrict__ kb,
    short* __restrict__ qb, short* __restrict__ vtb)
{
    int m0 = blockIdx.x * 64;
    __shared__ short vt[64][72];
    #pragma unroll
    for (int o = 0; o < 6; ++o) {
        int oct = o * 256 + threadIdx.x;          // 64 rows x 24 octets
        int row = oct / 24, c8 = (oct - row * 24) * 8;
        float s[8];
        #pragma unroll
        for (int j = 0; j < 8; ++j) s[j] = 0.f;
        #pragma unroll
        for (int cq = 0; cq < 4; ++cq) {
            s16x8 v = *(const s16x8*)&pp[((size_t)cq * 16384 + m0 + row) * 192 + c8];
            #pragma unroll
            for (int j = 0; j < 8; ++j) s[j] += bf2f(v[j]);
        }
        s16x8 r;
        #pragma unroll
        for (int j = 0; j < 4; ++j) {
            unsigned d = pack2(s[2 * j], s[2 * j + 1]);
            r[2 * j] = (short)d; r[2 * j + 1] = (short)(d >> 16);
        }
        if (c8 < 64)        *(s16x8*)&kb[(size_t)(m0 + row) * 64 + c8] = r;
        else if (c8 < 128)  *(s16x8*)&qb[(size_t)(m0 + row) * 64 + (c8 - 64)] = r;
        else {
            #pragma unroll
            for (int j = 0; j < 8; ++j) vt[c8 - 128 + j][row] = r[j];
        }
    }
    __syncthreads();
    int b = m0 >> 12, t0 = m0 & 4095;
    #pragma unroll
    for (int o = 0; o < 2; ++o) {
        int oct = o * 256 + threadIdx.x;          // 64 h x 8 octets
        int h = oct >> 3, tl = (oct & 7) * 8;
        s16x8 v = *(const s16x8*)&vt[h][tl];
        *(s16x8*)&vtb[(((size_t)b * 64 + h) << 12) + t0 + tl] = v;
    }
}

// ---------------------------------------------------------------------------
// Kernel 4: BARRIER-FREE flash partials, S^T form, fixed m=0 softmax.
// K/V frags direct global->VGPR (L2-served); LDS only for wave-local P.
// grid (64 qt, 8 chunk, 4 b) x 256 thr. po row: 64x64 O + 64 l, bf16.
// ---------------------------------------------------------------------------
__global__ __launch_bounds__(256) void flash_part(
    const short* __restrict__ qb, const short* __restrict__ kb,
    const short* __restrict__ vtb, const float* __restrict__ bias,
    short* __restrict__ po)
{
    int qt = blockIdx.x, c = blockIdx.y, b = blockIdx.z;
    int q0 = qt * QT;
    int kstart = c * CK;
    int kend = min(kstart + CK, q0 + QT);
    if (kstart >= kend) return;                   // block-uniform

    __shared__ __align__(16) short plds[4][16][72];

    int w = threadIdx.x >> 6, lane = threadIdx.x & 63;
    int l15 = lane & 15, quad = lane >> 4;
    int strip0 = q0 + w * 16;

    const short* qrow = qb + (size_t)(b * T_DIM + strip0 + l15) * 64;
    s16x8 aq0 = *(const s16x8*)(qrow + quad * 8);
    s16x8 aq1 = *(const s16x8*)(qrow + 32 + quad * 8);

    float l_sum = 0.f;
    f32x4 accO[4];
    #pragma unroll
    for (int nt = 0; nt < 4; ++nt) accO[nt] = (f32x4){0.f, 0.f, 0.f, 0.f};

    const float* brow = bias + (size_t)(strip0 + l15) * T_DIM;
    const short* kbb  = kb + ((size_t)b * T_DIM) * 64;
    const short* vbb  = vtb + ((size_t)b * 64 << 12);

    #pragma unroll 1
    for (int k0 = kstart; k0 < kend; k0 += KT) {
        // K fragments (QK A-operand): issued first
        s16x8 ak0[4], ak1[4];
        #pragma unroll
        for (int nt = 0; nt < 4; ++nt) {
            const short* kr = kbb + (size_t)(k0 + nt * 16 + l15) * 64;
            ak0[nt] = *(const s16x8*)(kr + quad * 8);
            ak1[nt] = *(const s16x8*)(kr + 32 + quad * 8);
        }
        // bias (needed after QK)
        f32x4 vb[4];
        #pragma unroll
        for (int nt = 0; nt < 4; ++nt)
            vb[nt] = *(const f32x4*)&brow[k0 + nt * 16 + quad * 4];
        // V fragments (PV B-operand): needed last
        s16x8 bv0[4], bv1[4];
        #pragma unroll
        for (int nt = 0; nt < 4; ++nt) {
            const short* vr = vbb + ((size_t)(nt * 16 + l15) << 12) + k0;
            bv0[nt] = *(const s16x8*)(vr + quad * 8);
            bv1[nt] = *(const s16x8*)(vr + 32 + quad * 8);
        }

        // S^T = K Q^T
        f32x4 accS[4];
        #pragma unroll
        for (int nt = 0; nt < 4; ++nt) {
            accS[nt] = (f32x4){0.f, 0.f, 0.f, 0.f};
            accS[nt] = __builtin_amdgcn_mfma_f32_16x16x32_bf16(ak0[nt], aq0, accS[nt], 0, 0, 0);
            accS[nt] = __builtin_amdgcn_mfma_f32_16x16x32_bf16(ak1[nt], aq1, accS[nt], 0, 0, 0);
        }

        int qrow_g = strip0 + l15;
        bool diag = (k0 + KT - 1 > strip0);
        #pragma unroll
        for (int nt = 0; nt < 4; ++nt) {
            float sv[4];
            #pragma unroll
            for (int r = 0; r < 4; ++r) {
                sv[r] = accS[nt][r] + vb[nt][r];
                if (diag && (k0 + nt * 16 + quad * 4 + r > qrow_g))
                    sv[r] = -__builtin_inff();
                float p = __expf(sv[r]);
                sv[r] = p;
                l_sum += p;
            }
            u32x2 d;
            d[0] = pack2(sv[0], sv[1]);
            d[1] = pack2(sv[2], sv[3]);
            *(u32x2*)&plds[w][l15][nt * 16 + quad * 4] = d;
        }

        // wave-local LDS round-trip (compiler orders via lgkmcnt; no barrier)
        s16x8 ap0 = *(const s16x8*)&plds[w][l15][quad * 8];
        s16x8 ap1 = *(const s16x8*)&plds[w][l15][32 + quad * 8];
        #pragma unroll
        for (int nt = 0; nt < 4; ++nt) {
            accO[nt] = __builtin_amdgcn_mfma_f32_16x16x32_bf16(ap0, bv0[nt], accO[nt], 0, 0, 0);
            accO[nt] = __builtin_amdgcn_mfma_f32_16x16x32_bf16(ap1, bv1[nt], accO[nt], 0, 0, 0);
        }
    }

    l_sum += __shfl_xor(l_sum, 16, 64);
    l_sum += __shfl_xor(l_sum, 32, 64);

    short* base = po + (size_t)(((b * 64 + qt) * 8) + c) * 4160;
    #pragma unroll
    for (int nt = 0; nt < 4; ++nt)
        #pragma unroll
        for (int r = 0; r < 4; ++r)
            base[(w * 16 + quad * 4 + r) * 64 + nt * 16 + l15] = f2bf(accO[nt][r]);
    if (quad == 0) base[4096 + w * 16 + l15] = f2bf(l_sum);
}

// ---------------------------------------------------------------------------
// Kernel 5: reduce partials + normalize. 1024 x 256.
// ---------------------------------------------------------------------------
__global__ __launch_bounds__(256) void flash_reduce(
    const short* __restrict__ po, float* __restrict__ out)
{
    int idx = blockIdx.x * 256 + threadIdx.x;
    int row = idx >> 4, c4 = idx & 15;
    int b = row >> 12, t = row & 4095;
    int qt = t >> 6, rloc = t & 63;
    int nc = (t >> 9) + 1;
    float o0 = 0.f, o1 = 0.f, o2 = 0.f, o3 = 0.f, l = 0.f;
    for (int cc = 0; cc < nc; ++cc) {
        const short* base = po + (size_t)(((b * 64 + qt) * 8) + cc) * 4160;
        const short* p = &base[rloc * 64 + c4 * 4];
        o0 += bf2f(p[0]); o1 += bf2f(p[1]); o2 += bf2f(p[2]); o3 += bf2f(p[3]);
        l += bf2f(base[4096 + rloc]);
    }
    float inv = 1.0f / l;
    f32x4 res = (f32x4){o0 * inv, o1 * inv, o2 * inv, o3 * inv};
    *(f32x4*)&out[(size_t)row * 64 + c4 * 4] = res;
}

// ---------------------------------------------------------------------------
extern "C" void kernel_launch(void* const* d_in, const int* in_sizes, int n_in,
                              void* d_out, int out_size, void* d_ws, size_t ws_size,
                              hipStream_t stream) {
    (void)in_sizes; (void)n_in; (void)out_size; (void)ws_size;
    const float* x    = (const float*)d_in[0];
    const float* bias = (const float*)d_in[1];
    const float* wk   = (const float*)d_in[2];
    const float* wq   = (const float*)d_in[3];
    const float* wv   = (const float*)d_in[4];
    float* out = (float*)d_out;

    short* wfrag = (short*)d_ws;                       // 196608
    short* kb    = wfrag + 196608;                     // 1048576 each
    short* qb    = kb + 1048576;
    short* vtb   = qb + 1048576;
    short* pp    = vtb + 1048576;                      // 12582912
    short* po    = pp + (size_t)12582912;              // 8519680

    prep_frag<<<dim3(32, 3), dim3(256), 0, stream>>>(wk, wq, wv, wfrag);
    proj_part<<<dim3(256, 4), dim3(256), 0, stream>>>(x, wfrag, pp);
    proj_combine<<<dim3(256), dim3(256), 0, stream>>>(pp, kb, qb, vtb);
    flash_part<<<dim3(64, 8, 4), dim3(256), 0, stream>>>(qb, kb, vtb, bias, po);
    flash_reduce<<<dim3(1024), dim3(256), 0, stream>>>(po, out);
}

// Round 5
// 229.348 us; speedup vs baseline: 1.3363x; 1.3363x over previous
//
#include <hip/hip_runtime.h>
#include <hip/hip_bf16.h>

// B=4, T=4096, C=1024, H=64 causal attention w/ RPE bias.
// Round 5: flash rebuilt around (a) 4-batches-per-block waves so bias loads
// dedup in L1/L2 (bias was the dominant traffic: 134MB logical), (b) K/V
// pre-permuted into MFMA fragment order by proj_combine so every flash load
// is a coalesced lane-consecutive 16B load -> no LDS staging, no barriers,
// no gathers. QT=32, CK=256: 1088 active blocks x 8 waves.

#define T_DIM 4096
#define C_DIM 1024
#define KT    64
#define CK    256

typedef __attribute__((ext_vector_type(8))) short s16x8;
typedef __attribute__((ext_vector_type(4))) float f32x4;
typedef __attribute__((ext_vector_type(2))) unsigned int u32x2;

__device__ __forceinline__ short f2bf(float f) {
    unsigned u = __builtin_bit_cast(unsigned, f);
    u += 0x7FFFu + ((u >> 16) & 1u);
    return (short)(u >> 16);
}
__device__ __forceinline__ unsigned pack2(float a, float b) {
    unsigned ua = __builtin_bit_cast(unsigned, a);
    unsigned ub = __builtin_bit_cast(unsigned, b);
    ua += 0x7FFFu + ((ua >> 16) & 1u);
    ub += 0x7FFFu + ((ub >> 16) & 1u);
    return __builtin_amdgcn_perm(ub, ua, 0x07060302u);
}
__device__ __forceinline__ float bf2f(short s) {
    unsigned u = ((unsigned)(unsigned short)s) << 16;
    return __builtin_bit_cast(float, u);
}
// prefix of active chunks before q-strip qt32 (nchunks(j) = j/8 + 1)
__device__ __forceinline__ int chunk_off(int qt32) {
    int g = qt32 >> 3, r = qt32 & 7;
    return qt32 + 4 * g * (g - 1) + r * g;
}

// ---------------------------------------------------------------------------
// Kernel 1: weights -> B-fragment order: wfrag[ksAll][mat][nt][lane][8] bf16.
// w_q scaled by 0.125. grid (32, 3) x 256.
// ---------------------------------------------------------------------------
__global__ __launch_bounds__(256) void prep_frag(
    const float* __restrict__ wk, const float* __restrict__ wq,
    const float* __restrict__ wv, short* __restrict__ wfrag)
{
    int ksAll = blockIdx.x, mat = blockIdx.y;
    const float* w = (mat == 0) ? wk : ((mat == 1) ? wq : wv);
    float sc = (mat == 1) ? 0.125f : 1.0f;
    int nt = threadIdx.x >> 6, lane = threadIdx.x & 63;
    int quad = lane >> 4, l15 = lane & 15;
    int h = nt * 16 + l15;
    int cb = ksAll * 32 + quad * 8;
    s16x8 v;
    #pragma unroll
    for (int j = 0; j < 8; ++j) v[j] = f2bf(w[(cb + j) * 64 + h] * sc);
    *(s16x8*)&wfrag[((ksAll * 12 + mat * 4 + nt) * 64 + lane) * 8] = v;
}

// ---------------------------------------------------------------------------
// Kernel 2: streaming projection partials (unchanged structure).
// grid (256, 4) x 256 thr. pp[cq][row][mat*64+h] bf16.
// ---------------------------------------------------------------------------
__global__ __launch_bounds__(256, 3) void proj_part(
    const float* __restrict__ x, const short* __restrict__ wfrag,
    short* __restrict__ pp)
{
    int w = threadIdx.x >> 6, lane = threadIdx.x & 63;
    int l15 = lane & 15, quad = lane >> 4;
    int row0 = (blockIdx.x * 4 + w) * 16;
    int cq = blockIdx.y;

    f32x4 acc[12];
    #pragma unroll
    for (int i = 0; i < 12; ++i) acc[i] = (f32x4){0.f, 0.f, 0.f, 0.f};

    const float* xrow = x + (size_t)(row0 + l15) * C_DIM + cq * 256;

    #pragma unroll 1
    for (int ksi = 0; ksi < 8; ++ksi) {
        int ks = (ksi + blockIdx.x) & 7;
        int ksAll = cq * 8 + ks;
        const s16x8* fb = (const s16x8*)&wfrag[(size_t)(ksAll * 12 * 64 + lane) * 8];
        f32x4 x0 = *(const f32x4*)(xrow + ks * 32 + quad * 8);
        f32x4 x1 = *(const f32x4*)(xrow + ks * 32 + quad * 8 + 4);
        s16x8 af;
        unsigned p0 = pack2(x0[0], x0[1]), p1 = pack2(x0[2], x0[3]);
        unsigned p2 = pack2(x1[0], x1[1]), p3 = pack2(x1[2], x1[3]);
        af[0] = (short)p0; af[1] = (short)(p0 >> 16);
        af[2] = (short)p1; af[3] = (short)(p1 >> 16);
        af[4] = (short)p2; af[5] = (short)(p2 >> 16);
        af[6] = (short)p3; af[7] = (short)(p3 >> 16);
        #pragma unroll
        for (int f = 0; f < 12; ++f) {
            s16x8 bf = fb[f * 64];
            acc[f] = __builtin_amdgcn_mfma_f32_16x16x32_bf16(af, bf, acc[f], 0, 0, 0);
        }
    }
    short* base = pp + (size_t)cq * 16384 * 192;
    #pragma unroll
    for (int f = 0; f < 12; ++f) {
        int mat = f >> 2, nt = f & 3;
        #pragma unroll
        for (int r = 0; r < 4; ++r)
            base[(size_t)(row0 + quad * 4 + r) * 192 + mat * 64 + nt * 16 + l15] =
                f2bf(acc[f][r]);
    }
}

// ---------------------------------------------------------------------------
// Kernel 3: combine 4 partials -> qb row-major, kfrag (QK A-layout),
// vfrag (PV B-layout). grid 256 x 256, 64 rows (= 64 keys) per block.
// kfrag[((b*256+kt16)*2+ks)*64+lane][8]: elem j = K[kt16*16+l15][ks*32+quad*8+j]
// vfrag[((b*128+kt32)*4+nt)*64+lane][8]: elem j = V[kt32*32+quad*8+j][nt*16+l15]
// ---------------------------------------------------------------------------
__global__ __launch_bounds__(256) void proj_combine(
    const short* __restrict__ pp, short* __restrict__ qb,
    short* __restrict__ kfrag, short* __restrict__ vfrag)
{
    int m0 = blockIdx.x * 64;
    int b = m0 >> 12, t0 = m0 & 4095;
    __shared__ short vt[64][72];
    #pragma unroll
    for (int o = 0; o < 6; ++o) {
        int oct = o * 256 + threadIdx.x;          // 64 rows x 24 octets
        int row = oct / 24, c8 = (oct - row * 24) * 8;
        float s[8];
        #pragma unroll
        for (int j = 0; j < 8; ++j) s[j] = 0.f;
        #pragma unroll
        for (int cq = 0; cq < 4; ++cq) {
            s16x8 v = *(const s16x8*)&pp[((size_t)cq * 16384 + m0 + row) * 192 + c8];
            #pragma unroll
            for (int j = 0; j < 8; ++j) s[j] += bf2f(v[j]);
        }
        s16x8 r;
        #pragma unroll
        for (int j = 0; j < 4; ++j) {
            unsigned d = pack2(s[2 * j], s[2 * j + 1]);
            r[2 * j] = (short)d; r[2 * j + 1] = (short)(d >> 16);
        }
        int t = t0 + row;
        if (c8 < 64) {
            // K octet: h = c8..c8+7 -> kfrag
            int quad = (c8 >> 3) & 3, ks = c8 >> 5;
            int lane = quad * 16 + (t & 15);
            *(s16x8*)&kfrag[(size_t)(((b * 256 + (t >> 4)) * 2 + ks) * 64 + lane) * 8] = r;
        } else if (c8 < 128) {
            *(s16x8*)&qb[(size_t)(m0 + row) * 64 + (c8 - 64)] = r;
        } else {
            #pragma unroll
            for (int j = 0; j < 8; ++j) vt[c8 - 128 + j][row] = r[j];
        }
    }
    __syncthreads();
    #pragma unroll
    for (int rep = 0; rep < 2; ++rep) {
        int id = rep * 256 + threadIdx.x;         // 512 = 2 kl x 4 nt x 64 lane
        int lane = id & 63, nt = (id >> 6) & 3, kl = id >> 8;
        int l15 = lane & 15, quad = lane >> 4;
        s16x8 v = *(const s16x8*)&vt[nt * 16 + l15][kl * 32 + quad * 8];
        *(s16x8*)&vfrag[(size_t)(((b * 128 + (t0 >> 5) + kl) * 4 + nt) * 64 + lane) * 8] = v;
    }
}

// ---------------------------------------------------------------------------
// Kernel 4: flash partials. Block = 8 waves: (b = w&3) x (strip = w>>2).
// Barrier-free; all loads coalesced 16B; bias dedup'd across b-waves via L1.
// grid (128 qt32, 16 chunk); early-exit c >= qt32/8+1.
// po slot (chunk_off(qt32)+c)*4+b : 32x64 O + 32 l, bf16.
// ---------------------------------------------------------------------------
__global__ __launch_bounds__(512, 4) void flash_part(
    const short* __restrict__ qb, const short* __restrict__ kfrag,
    const short* __restrict__ vfrag, const float* __restrict__ bias,
    short* __restrict__ po)
{
    int qt = blockIdx.x, c = blockIdx.y;
    if (c > (qt >> 3)) return;                    // block-uniform
    int q0 = qt * 32;
    int kstart = c * CK;
    int kend = min(kstart + CK, q0 + 32);

    __shared__ __align__(16) short plds[8][16][72];

    int w = threadIdx.x >> 6, lane = threadIdx.x & 63;
    int b = w & 3, sl = w >> 2;
    int l15 = lane & 15, quad = lane >> 4;
    int strip0 = q0 + sl * 16;

    const short* qrow = qb + (size_t)(b * T_DIM + strip0 + l15) * 64;
    s16x8 aq0 = *(const s16x8*)(qrow + quad * 8);
    s16x8 aq1 = *(const s16x8*)(qrow + 32 + quad * 8);

    float l_sum = 0.f;
    f32x4 accO[4];
    #pragma unroll
    for (int nt = 0; nt < 4; ++nt) accO[nt] = (f32x4){0.f, 0.f, 0.f, 0.f};

    const float* brow = bias + (size_t)(strip0 + l15) * T_DIM;
    const short* kfb = kfrag + (size_t)b * 256 * 2 * 512;
    const short* vfb = vfrag + (size_t)b * 128 * 4 * 512;

    #pragma unroll 1
    for (int k0 = kstart; k0 < kend; k0 += KT) {
        int kt16 = k0 >> 4, kt32 = k0 >> 5;
        // K A-frags: coalesced 16B, 2 per key-16-tile
        s16x8 ak0[4], ak1[4];
        #pragma unroll
        for (int nt = 0; nt < 4; ++nt) {
            const short* kp = kfb + (size_t)((kt16 + nt) * 2) * 512 + lane * 8;
            ak0[nt] = *(const s16x8*)kp;
            ak1[nt] = *(const s16x8*)(kp + 512);
        }
        // bias: shared across the 4 b-waves of this strip (L1 dedup)
        f32x4 vb[4];
        #pragma unroll
        for (int nt = 0; nt < 4; ++nt)
            vb[nt] = *(const f32x4*)&brow[k0 + nt * 16 + quad * 4];

        // S^T = K Q^T
        f32x4 accS[4];
        #pragma unroll
        for (int nt = 0; nt < 4; ++nt) {
            accS[nt] = (f32x4){0.f, 0.f, 0.f, 0.f};
            accS[nt] = __builtin_amdgcn_mfma_f32_16x16x32_bf16(ak0[nt], aq0, accS[nt], 0, 0, 0);
            accS[nt] = __builtin_amdgcn_mfma_f32_16x16x32_bf16(ak1[nt], aq1, accS[nt], 0, 0, 0);
        }

        // V B-frags issued here so latency hides behind exp/mask VALU
        s16x8 bv0[4], bv1[4];
        #pragma unroll
        for (int nt = 0; nt < 4; ++nt) {
            const short* vp = vfb + (size_t)(kt32 * 4 + nt) * 512 + lane * 8;
            bv0[nt] = *(const s16x8*)vp;
            bv1[nt] = *(const s16x8*)(vp + 2048);
        }

        int qrow_g = strip0 + l15;
        bool diag = (k0 + KT - 1 > strip0);
        #pragma unroll
        for (int nt = 0; nt < 4; ++nt) {
            float sv[4];
            #pragma unroll
            for (int r = 0; r < 4; ++r) {
                sv[r] = accS[nt][r] + vb[nt][r];
                if (diag && (k0 + nt * 16 + quad * 4 + r > qrow_g))
                    sv[r] = -__builtin_inff();
                float p = __expf(sv[r]);
                sv[r] = p;
                l_sum += p;
            }
            u32x2 d;
            d[0] = pack2(sv[0], sv[1]);
            d[1] = pack2(sv[2], sv[3]);
            *(u32x2*)&plds[w][l15][nt * 16 + quad * 4] = d;
        }

        // wave-local LDS transpose round-trip (no barrier: same wave)
        s16x8 ap0 = *(const s16x8*)&plds[w][l15][quad * 8];
        s16x8 ap1 = *(const s16x8*)&plds[w][l15][32 + quad * 8];
        #pragma unroll
        for (int nt = 0; nt < 4; ++nt) {
            accO[nt] = __builtin_amdgcn_mfma_f32_16x16x32_bf16(ap0, bv0[nt], accO[nt], 0, 0, 0);
            accO[nt] = __builtin_amdgcn_mfma_f32_16x16x32_bf16(ap1, bv1[nt], accO[nt], 0, 0, 0);
        }
    }

    l_sum += __shfl_xor(l_sum, 16, 64);
    l_sum += __shfl_xor(l_sum, 32, 64);

    short* base = po + (size_t)((chunk_off(qt) + c) * 4 + b) * 2080;
    #pragma unroll
    for (int nt = 0; nt < 4; ++nt)
        #pragma unroll
        for (int r = 0; r < 4; ++r)
            base[(sl * 16 + quad * 4 + r) * 64 + nt * 16 + l15] = f2bf(accO[nt][r]);
    if (quad == 0) base[2048 + sl * 16 + l15] = f2bf(l_sum);
}

// ---------------------------------------------------------------------------
// Kernel 5: reduce partials + normalize. 1024 x 256.
// ---------------------------------------------------------------------------
__global__ __launch_bounds__(256) void flash_reduce(
    const short* __restrict__ po, float* __restrict__ out)
{
    int idx = blockIdx.x * 256 + threadIdx.x;
    int row = idx >> 4, c4 = idx & 15;
    int b = row >> 12, t = row & 4095;
    int qt = t >> 5, rloc = t & 31;
    int nc = (t >> 8) + 1;
    int off = chunk_off(qt);
    float o0 = 0.f, o1 = 0.f, o2 = 0.f, o3 = 0.f, l = 0.f;
    #pragma unroll 1
    for (int cc = 0; cc < nc; ++cc) {
        const short* base = po + (size_t)((off + cc) * 4 + b) * 2080;
        const short* p = &base[rloc * 64 + c4 * 4];
        o0 += bf2f(p[0]); o1 += bf2f(p[1]); o2 += bf2f(p[2]); o3 += bf2f(p[3]);
        l += bf2f(base[2048 + rloc]);
    }
    float inv = 1.0f / l;
    f32x4 res = (f32x4){o0 * inv, o1 * inv, o2 * inv, o3 * inv};
    *(f32x4*)&out[(size_t)row * 64 + c4 * 4] = res;
}

// ---------------------------------------------------------------------------
extern "C" void kernel_launch(void* const* d_in, const int* in_sizes, int n_in,
                              void* d_out, int out_size, void* d_ws, size_t ws_size,
                              hipStream_t stream) {
    (void)in_sizes; (void)n_in; (void)out_size; (void)ws_size;
    const float* x    = (const float*)d_in[0];
    const float* bias = (const float*)d_in[1];
    const float* wk   = (const float*)d_in[2];
    const float* wq   = (const float*)d_in[3];
    const float* wv   = (const float*)d_in[4];
    float* out = (float*)d_out;

    short* wfrag = (short*)d_ws;                       // 196608
    short* qb    = wfrag + 196608;                     // 1048576 each
    short* kfrag = qb + 1048576;
    short* vfrag = kfrag + 1048576;
    short* pp    = vfrag + 1048576;                    // 12582912
    short* po    = pp + (size_t)12582912;              // 4352*2080 = 9052160

    prep_frag<<<dim3(32, 3), dim3(256), 0, stream>>>(wk, wq, wv, wfrag);
    proj_part<<<dim3(256, 4), dim3(256), 0, stream>>>(x, wfrag, pp);
    proj_combine<<<dim3(256), dim3(256), 0, stream>>>(pp, qb, kfrag, vfrag);
    flash_part<<<dim3(128, 16), dim3(512), 0, stream>>>(qb, kfrag, vfrag, bias, po);
    flash_reduce<<<dim3(1024), dim3(256), 0, stream>>>(po, out);
}

// Round 7
// 222.736 us; speedup vs baseline: 1.3760x; 1.0297x over previous
//
#include <hip/hip_runtime.h>
#include <hip/hip_bf16.h>

// B=4, T=4096, C=1024, H=64 causal attention w/ RPE bias.
// Round 6 (resubmit; round-6 bench was an infra failure):
// (a) proj fused to ONE kernel: split-C=2, in-block LDS combine,
// direct emission of qb + kfrag (QK A-layout) + vfrag (PV B-layout).
// (b) flash software-pipelined: KT=32, A/B double-buffered K-frags + bias
// (bias is single-use HBM traffic -> needs deep flight), ~16 waves/CU.
// 4 kernels total; ws 25MB.

#define T_DIM 4096
#define C_DIM 1024
#define CK    256          // flash key-chunk (keys per po partial)

typedef __attribute__((ext_vector_type(8))) short s16x8;
typedef __attribute__((ext_vector_type(4))) float f32x4;
typedef __attribute__((ext_vector_type(2))) unsigned int u32x2;

__device__ __forceinline__ short f2bf(float f) {
    unsigned u = __builtin_bit_cast(unsigned, f);
    u += 0x7FFFu + ((u >> 16) & 1u);
    return (short)(u >> 16);
}
__device__ __forceinline__ unsigned pack2(float a, float b) {
    unsigned ua = __builtin_bit_cast(unsigned, a);
    unsigned ub = __builtin_bit_cast(unsigned, b);
    ua += 0x7FFFu + ((ua >> 16) & 1u);
    ub += 0x7FFFu + ((ub >> 16) & 1u);
    return __builtin_amdgcn_perm(ub, ua, 0x07060302u);
}
__device__ __forceinline__ float bf2f(short s) {
    unsigned u = ((unsigned)(unsigned short)s) << 16;
    return __builtin_bit_cast(float, u);
}
// prefix of active 256-key chunks before 16-q-strip qt: nchunks(j)=j/16+1
__device__ __forceinline__ int chunk_off(int qt) {
    int g = qt >> 4, r = qt & 15;
    return qt + 8 * g * (g - 1) + r * g;
}

// ---------------------------------------------------------------------------
// Kernel 1: weights -> B-fragment order: wfrag[ksAll][mat][nt][lane][8] bf16.
// elem j of (ksAll,mat,nt,lane=quad*16+l15): w[c=ksAll*32+quad*8+j][h=nt*16+l15]
// w_q scaled by 0.125. grid (32, 3) x 256.
// ---------------------------------------------------------------------------
__global__ __launch_bounds__(256) void prep_frag(
    const float* __restrict__ wk, const float* __restrict__ wq,
    const float* __restrict__ wv, short* __restrict__ wfrag)
{
    int ksAll = blockIdx.x, mat = blockIdx.y;
    const float* w = (mat == 0) ? wk : ((mat == 1) ? wq : wv);
    float sc = (mat == 1) ? 0.125f : 1.0f;
    int nt = threadIdx.x >> 6, lane = threadIdx.x & 63;
    int quad = lane >> 4, l15 = lane & 15;
    int h = nt * 16 + l15;
    int cb = ksAll * 32 + quad * 8;
    s16x8 v;
    #pragma unroll
    for (int j = 0; j < 8; ++j) v[j] = f2bf(w[(cb + j) * 64 + h] * sc);
    *(s16x8*)&wfrag[((ksAll * 12 + mat * 4 + nt) * 64 + lane) * 8] = v;
}

// ---------------------------------------------------------------------------
// Kernel 2: fused projection. grid 256 x 512 (8 waves = 4 row-groups x 2
// C-halves). MFMA partials in regs; h=1 waves park partials in LDS; h=0
// combine; emit qb row-major, kfrag, vfrag (V transposed via vsep).
// ---------------------------------------------------------------------------
__global__ __launch_bounds__(512, 2) void proj_fused(
    const float* __restrict__ x, const short* __restrict__ wfrag,
    short* __restrict__ qb, short* __restrict__ kfrag, short* __restrict__ vfrag)
{
    __shared__ __align__(16) short comb[4][16][136];  // K cols 0..63, Q 64..127
    __shared__ __align__(16) short vsep[64][72];      // V transposed [h][key]

    int tid = threadIdx.x;
    int w = tid >> 6, lane = tid & 63;
    int g = w & 3, h = w >> 2;
    int l15 = lane & 15, quad = lane >> 4;
    int m0 = blockIdx.x * 64;
    int row0 = m0 + g * 16;

    f32x4 acc[12];
    #pragma unroll
    for (int i = 0; i < 12; ++i) acc[i] = (f32x4){0.f, 0.f, 0.f, 0.f};

    const float* xrow = x + (size_t)(row0 + l15) * C_DIM + h * 512;

    #pragma unroll 1
    for (int ks = 0; ks < 16; ++ks) {
        int ksAll = h * 16 + ks;
        const s16x8* fb = (const s16x8*)&wfrag[(size_t)(ksAll * 12 * 64 + lane) * 8];
        f32x4 x0 = *(const f32x4*)(xrow + ks * 32 + quad * 8);
        f32x4 x1 = *(const f32x4*)(xrow + ks * 32 + quad * 8 + 4);
        s16x8 af;
        unsigned p0 = pack2(x0[0], x0[1]), p1 = pack2(x0[2], x0[3]);
        unsigned p2 = pack2(x1[0], x1[1]), p3 = pack2(x1[2], x1[3]);
        af[0] = (short)p0; af[1] = (short)(p0 >> 16);
        af[2] = (short)p1; af[3] = (short)(p1 >> 16);
        af[4] = (short)p2; af[5] = (short)(p2 >> 16);
        af[6] = (short)p3; af[7] = (short)(p3 >> 16);
        #pragma unroll
        for (int f = 0; f < 12; ++f) {
            s16x8 bf = fb[f * 64];
            acc[f] = __builtin_amdgcn_mfma_f32_16x16x32_bf16(af, bf, acc[f], 0, 0, 0);
        }
    }

    // ---- in-block combine: h=1 parks partials, h=0 adds ----
    if (h == 1) {
        #pragma unroll
        for (int f = 0; f < 8; ++f)
            #pragma unroll
            for (int r = 0; r < 4; ++r)
                comb[g][quad * 4 + r][(f >> 2) * 64 + (f & 3) * 16 + l15] = f2bf(acc[f][r]);
        #pragma unroll
        for (int f = 8; f < 12; ++f)
            #pragma unroll
            for (int r = 0; r < 4; ++r)
                vsep[(f & 3) * 16 + l15][g * 16 + quad * 4 + r] = f2bf(acc[f][r]);
    }
    __syncthreads();
    if (h == 0) {
        #pragma unroll
        for (int f = 0; f < 8; ++f)
            #pragma unroll
            for (int r = 0; r < 4; ++r) {
                int col = (f >> 2) * 64 + (f & 3) * 16 + l15, rr = quad * 4 + r;
                comb[g][rr][col] = f2bf(acc[f][r] + bf2f(comb[g][rr][col]));
            }
        #pragma unroll
        for (int f = 8; f < 12; ++f)
            #pragma unroll
            for (int r = 0; r < 4; ++r) {
                int hh = (f & 3) * 16 + l15, kk = g * 16 + quad * 4 + r;
                vsep[hh][kk] = f2bf(acc[f][r] + bf2f(vsep[hh][kk]));
            }
    }
    __syncthreads();

    // ---- emission (512 threads) ----
    int b = m0 >> 12, t0 = m0 & 4095;
    {   // qb: 64 rows x 64 cols (cols 64..127 of comb)
        int row = tid >> 3, ch = tid & 7;
        s16x8 v = *(const s16x8*)&comb[row >> 4][row & 15][64 + ch * 8];
        *(s16x8*)&qb[(size_t)(m0 + row) * 64 + ch * 8] = v;
    }
    {   // kfrag: 4 kt x 2 ks tiles
        int kt = w & 3, ks = w >> 2;
        s16x8 v = *(const s16x8*)&comb[kt][l15][ks * 32 + quad * 8];
        *(s16x8*)&kfrag[(size_t)(((b * 256 + (t0 >> 4) + kt) * 2 + ks) * 64 + lane) * 8] = v;
    }
    {   // vfrag: 2 kt32 x 4 nt tiles (16B reads from vsep, key-contiguous)
        int kt32 = w & 1, nt = w >> 1;
        s16x8 v = *(const s16x8*)&vsep[nt * 16 + l15][kt32 * 32 + quad * 8];
        *(s16x8*)&vfrag[(size_t)(((b * 128 + (t0 >> 5) + kt32) * 4 + nt) * 64 + lane) * 8] = v;
    }
}

// ---------------------------------------------------------------------------
// Kernel 3: flash partials, S^T form, fixed m=0 softmax, software-pipelined.
// Block = 4 waves = 4 batches, one 16-q strip. grid (256 qt, 16 chunk),
// early-exit c > qt/16. KT=32 tiles; K-frags + bias double-buffered (A/B).
// po slot (chunk_off(qt)+c)*4+b : 16x64 O + 16 l, bf16 (1040 shorts).
// ---------------------------------------------------------------------------
#define LOADST(AK, VB, k0) do {                                               \
    int _kt16 = (k0) >> 4;                                                    \
    _Pragma("unroll")                                                         \
    for (int _n = 0; _n < 2; ++_n) {                                          \
        const short* _kp = kfb + (size_t)((_kt16 + _n) * 2) * 512 + lane * 8; \
        AK[_n * 2]     = *(const s16x8*)_kp;                                  \
        AK[_n * 2 + 1] = *(const s16x8*)(_kp + 512);                          \
    }                                                                         \
    _Pragma("unroll")                                                         \
    for (int _n = 0; _n < 2; ++_n)                                            \
        VB[_n] = *(const f32x4*)&brow[(k0) + _n * 16 + quad * 4];             \
} while (0)

#define COMPUTEST(AK, VB, k0) do {                                            \
    int _kt32 = (k0) >> 5;                                                    \
    s16x8 _bv[4];                                                             \
    _Pragma("unroll")                                                         \
    for (int _n = 0; _n < 4; ++_n)                                            \
        _bv[_n] = *(const s16x8*)(vfb + (size_t)(_kt32 * 4 + _n) * 512 + lane * 8); \
    f32x4 _aS[2];                                                             \
    _Pragma("unroll")                                                         \
    for (int _n = 0; _n < 2; ++_n) {                                          \
        _aS[_n] = (f32x4){0.f, 0.f, 0.f, 0.f};                                \
        _aS[_n] = __builtin_amdgcn_mfma_f32_16x16x32_bf16(AK[_n*2],   aq0, _aS[_n], 0, 0, 0); \
        _aS[_n] = __builtin_amdgcn_mfma_f32_16x16x32_bf16(AK[_n*2+1], aq1, _aS[_n], 0, 0, 0); \
    }                                                                         \
    _Pragma("unroll")                                                         \
    for (int _n = 0; _n < 2; ++_n) {                                          \
        float _sv[4];                                                         \
        _Pragma("unroll")                                                     \
        for (int _r = 0; _r < 4; ++_r) {                                      \
            _sv[_r] = _aS[_n][_r] + VB[_n][_r];                               \
            if (mask_on && ((k0) + _n * 16 + quad * 4 + _r > strip0 + l15))   \
                _sv[_r] = -__builtin_inff();                                  \
            float _p = __expf(_sv[_r]);                                       \
            _sv[_r] = _p;                                                     \
            l_sum += _p;                                                      \
        }                                                                     \
        u32x2 _d;                                                             \
        _d[0] = pack2(_sv[0], _sv[1]);                                        \
        _d[1] = pack2(_sv[2], _sv[3]);                                        \
        *(u32x2*)&plds[w][l15][_n * 16 + quad * 4] = _d;                      \
    }                                                                         \
    s16x8 _ap = *(const s16x8*)&plds[w][l15][quad * 8];                       \
    _Pragma("unroll")                                                         \
    for (int _n = 0; _n < 4; ++_n)                                            \
        accO[_n] = __builtin_amdgcn_mfma_f32_16x16x32_bf16(_ap, _bv[_n], accO[_n], 0, 0, 0); \
} while (0)

__global__ __launch_bounds__(256, 4) void flash_part(
    const short* __restrict__ qb, const short* __restrict__ kfrag,
    const short* __restrict__ vfrag, const float* __restrict__ bias,
    short* __restrict__ po)
{
    int qt = blockIdx.x, c = blockIdx.y;
    if (c > (qt >> 4)) return;                    // block-uniform early exit
    int q0 = qt * 16;
    int kstart = c * CK;
    int kend = min(kstart + CK, q0 + 16);

    __shared__ __align__(16) short plds[4][16][40];

    int w = threadIdx.x >> 6, lane = threadIdx.x & 63;  // w = batch
    int b = w;
    int l15 = lane & 15, quad = lane >> 4;
    int strip0 = q0;

    const short* qrow = qb + (size_t)(b * T_DIM + strip0 + l15) * 64;
    s16x8 aq0 = *(const s16x8*)(qrow + quad * 8);
    s16x8 aq1 = *(const s16x8*)(qrow + 32 + quad * 8);

    float l_sum = 0.f;
    f32x4 accO[4];
    #pragma unroll
    for (int nt = 0; nt < 4; ++nt) accO[nt] = (f32x4){0.f, 0.f, 0.f, 0.f};

    const float* brow = bias + (size_t)(strip0 + l15) * T_DIM;
    const short* kfb = kfrag + (size_t)b * 256 * 2 * 512;
    const short* vfb = vfrag + (size_t)b * 128 * 4 * 512;
    bool mask_on = (kend > strip0);               // only final chunk masks

    s16x8 akA[4], akB[4];
    f32x4 vbA[2], vbB[2];
    int k0 = kstart;
    LOADST(akA, vbA, k0);
    while (true) {
        int k1 = k0 + 32;
        bool more = (k1 < kend);
        if (more) LOADST(akB, vbB, k1);
        COMPUTEST(akA, vbA, k0);
        if (!more) break;
        k0 = k1; k1 = k0 + 32;
        bool more2 = (k1 < kend);
        if (more2) LOADST(akA, vbA, k1);
        COMPUTEST(akB, vbB, k0);
        if (!more2) break;
        k0 = k1;
    }

    l_sum += __shfl_xor(l_sum, 16, 64);
    l_sum += __shfl_xor(l_sum, 32, 64);

    short* base = po + (size_t)((chunk_off(qt) + c) * 4 + b) * 1040;
    #pragma unroll
    for (int nt = 0; nt < 4; ++nt)
        #pragma unroll
        for (int r = 0; r < 4; ++r)
            base[(quad * 4 + r) * 64 + nt * 16 + l15] = f2bf(accO[nt][r]);
    if (quad == 0) base[1024 + l15] = f2bf(l_sum);
}

// ---------------------------------------------------------------------------
// Kernel 4: reduce partials + normalize. 1024 x 256.
// ---------------------------------------------------------------------------
__global__ __launch_bounds__(256) void flash_reduce(
    const short* __restrict__ po, float* __restrict__ out)
{
    int idx = blockIdx.x * 256 + threadIdx.x;
    int row = idx >> 4, c4 = idx & 15;
    int b = row >> 12, t = row & 4095;
    int qt = t >> 4, rloc = t & 15;
    int nc = (t >> 8) + 1;
    int off = chunk_off(qt);
    float o0 = 0.f, o1 = 0.f, o2 = 0.f, o3 = 0.f, l = 0.f;
    #pragma unroll 1
    for (int cc = 0; cc < nc; ++cc) {
        const short* base = po + (size_t)((off + cc) * 4 + b) * 1040;
        const short* p = &base[rloc * 64 + c4 * 4];
        o0 += bf2f(p[0]); o1 += bf2f(p[1]); o2 += bf2f(p[2]); o3 += bf2f(p[3]);
        l += bf2f(base[1024 + rloc]);
    }
    float inv = 1.0f / l;
    f32x4 res = (f32x4){o0 * inv, o1 * inv, o2 * inv, o3 * inv};
    *(f32x4*)&out[(size_t)row * 64 + c4 * 4] = res;
}

// ---------------------------------------------------------------------------
extern "C" void kernel_launch(void* const* d_in, const int* in_sizes, int n_in,
                              void* d_out, int out_size, void* d_ws, size_t ws_size,
                              hipStream_t stream) {
    (void)in_sizes; (void)n_in; (void)out_size; (void)ws_size;
    const float* x    = (const float*)d_in[0];
    const float* bias = (const float*)d_in[1];
    const float* wk   = (const float*)d_in[2];
    const float* wq   = (const float*)d_in[3];
    const float* wv   = (const float*)d_in[4];
    float* out = (float*)d_out;

    short* wfrag = (short*)d_ws;                       // 196608
    short* qb    = wfrag + 196608;                     // 1048576 each
    short* kfrag = qb + 1048576;
    short* vfrag = kfrag + 1048576;
    short* po    = vfrag + 1048576;                    // 2176*4*1040 = 9052160

    prep_frag<<<dim3(32, 3), dim3(256), 0, stream>>>(wk, wq, wv, wfrag);
    proj_fused<<<dim3(256), dim3(512), 0, stream>>>(x, wfrag, qb, kfrag, vfrag);
    flash_part<<<dim3(256, 16), dim3(256), 0, stream>>>(qb, kfrag, vfrag, bias, po);
    flash_reduce<<<dim3(1024), dim3(256), 0, stream>>>(po, out);
}

// Round 8
// 202.514 us; speedup vs baseline: 1.5134x; 1.0999x over previous
//
#include <hip/hip_runtime.h>
#include <hip/hip_bf16.h>

// B=4, T=4096, C=1024, H=64 causal attention w/ RPE bias.
// Round 8: kill the row-gather loads. Root cause of 4 rounds of invariant
// time: bias (flash) and x (proj) were loaded with lane->row indexing =
// 16 cache lines per instruction (TA-serialized, ~0.6 TB/s). Both now
// staged through LDS with row-parallel coalesced loads (1 contiguous KB
// per wave-instruction); MFMA fragment gathers happen in LDS where they
// are free. proj: 32-row blocks, x-stage union'd with combine buffers.
// flash: 16x256 fp32 bias tile staged once per block, k-loop barrier-free.

#define T_DIM 4096
#define C_DIM 1024
#define CK    256          // flash key-chunk (keys per po partial)

typedef __attribute__((ext_vector_type(8))) short s16x8;
typedef __attribute__((ext_vector_type(4))) float f32x4;
typedef __attribute__((ext_vector_type(2))) unsigned int u32x2;

__device__ __forceinline__ short f2bf(float f) {
    unsigned u = __builtin_bit_cast(unsigned, f);
    u += 0x7FFFu + ((u >> 16) & 1u);
    return (short)(u >> 16);
}
__device__ __forceinline__ unsigned pack2(float a, float b) {
    unsigned ua = __builtin_bit_cast(unsigned, a);
    unsigned ub = __builtin_bit_cast(unsigned, b);
    ua += 0x7FFFu + ((ua >> 16) & 1u);
    ub += 0x7FFFu + ((ub >> 16) & 1u);
    return __builtin_amdgcn_perm(ub, ua, 0x07060302u);
}
__device__ __forceinline__ float bf2f(short s) {
    unsigned u = ((unsigned)(unsigned short)s) << 16;
    return __builtin_bit_cast(float, u);
}
// prefix of active 256-key chunks before 16-q-strip qt: nchunks(j)=j/16+1
__device__ __forceinline__ int chunk_off(int qt) {
    int g = qt >> 4, r = qt & 15;
    return qt + 8 * g * (g - 1) + r * g;
}

// ---------------------------------------------------------------------------
// Kernel 1: weights -> B-fragment order: wfrag[ksAll][mat][nt][lane][8] bf16.
// w_q scaled by 0.125. grid (32, 3) x 256.
// ---------------------------------------------------------------------------
__global__ __launch_bounds__(256) void prep_frag(
    const float* __restrict__ wk, const float* __restrict__ wq,
    const float* __restrict__ wv, short* __restrict__ wfrag)
{
    int ksAll = blockIdx.x, mat = blockIdx.y;
    const float* w = (mat == 0) ? wk : ((mat == 1) ? wq : wv);
    float sc = (mat == 1) ? 0.125f : 1.0f;
    int nt = threadIdx.x >> 6, lane = threadIdx.x & 63;
    int quad = lane >> 4, l15 = lane & 15;
    int h = nt * 16 + l15;
    int cb = ksAll * 32 + quad * 8;
    s16x8 v;
    #pragma unroll
    for (int j = 0; j < 8; ++j) v[j] = f2bf(w[(cb + j) * 64 + h] * sc);
    *(s16x8*)&wfrag[((ksAll * 12 + mat * 4 + nt) * 64 + lane) * 8] = v;
}

// ---------------------------------------------------------------------------
// Kernel 2: fused projection, 32 rows/block, x staged coalesced into LDS.
// grid 512 x 256 (4 waves = 2 row-tiles x 2 C-halves). Emits qb row-major,
// kfrag (QK A-layout), vfrag (PV B-layout).
// ---------------------------------------------------------------------------
union ProjSmem {
    short xs[32][1032];                 // staged x rows (bf16), pad 1032
    struct {
        short comb[2][16][136];         // K cols 0..63, Q cols 64..127
        short vsep[64][40];             // V transposed [h][key 0..31 +pad]
    } c;
};

__global__ __launch_bounds__(256, 2) void proj_fused(
    const float* __restrict__ x, const short* __restrict__ wfrag,
    short* __restrict__ qb, short* __restrict__ kfrag, short* __restrict__ vfrag)
{
    __shared__ __align__(16) ProjSmem sm;

    int tid = threadIdx.x;
    int w = tid >> 6, lane = tid & 63;
    int rt = w >> 1, h = w & 1;
    int l15 = lane & 15, quad = lane >> 4;
    int m0 = blockIdx.x * 32;

    // ---- stage x: 32 passes, each = one full row, lanes along C ----
    #pragma unroll 8
    for (int p = 0; p < 32; ++p) {
        f32x4 v = *(const f32x4*)&x[(size_t)(m0 + p) * C_DIM + tid * 4];
        u32x2 d;
        d[0] = pack2(v[0], v[1]);
        d[1] = pack2(v[2], v[3]);
        *(u32x2*)&sm.xs[p][tid * 4] = d;
    }
    __syncthreads();

    // ---- MFMA: wave (rt,h) does rows rt*16.., ksAll = h*16..h*16+15 ----
    f32x4 acc[12];
    #pragma unroll
    for (int i = 0; i < 12; ++i) acc[i] = (f32x4){0.f, 0.f, 0.f, 0.f};

    #pragma unroll 1
    for (int ks = 0; ks < 16; ++ks) {
        int ksAll = h * 16 + ks;
        s16x8 af = *(const s16x8*)&sm.xs[rt * 16 + l15][ksAll * 32 + quad * 8];
        const s16x8* fb = (const s16x8*)&wfrag[(size_t)(ksAll * 12 * 64 + lane) * 8];
        #pragma unroll
        for (int f = 0; f < 12; ++f) {
            s16x8 bf = fb[f * 64];
            acc[f] = __builtin_amdgcn_mfma_f32_16x16x32_bf16(af, bf, acc[f], 0, 0, 0);
        }
    }
    __syncthreads();   // all waves done reading xs; union -> combine buffers

    // ---- combine: h=1 parks, h=0 adds ----
    if (h == 1) {
        #pragma unroll
        for (int f = 0; f < 8; ++f)
            #pragma unroll
            for (int r = 0; r < 4; ++r)
                sm.c.comb[rt][quad * 4 + r][(f >> 2) * 64 + (f & 3) * 16 + l15] = f2bf(acc[f][r]);
        #pragma unroll
        for (int f = 8; f < 12; ++f)
            #pragma unroll
            for (int r = 0; r < 4; ++r)
                sm.c.vsep[(f & 3) * 16 + l15][rt * 16 + quad * 4 + r] = f2bf(acc[f][r]);
    }
    __syncthreads();
    if (h == 0) {
        #pragma unroll
        for (int f = 0; f < 8; ++f)
            #pragma unroll
            for (int r = 0; r < 4; ++r) {
                int col = (f >> 2) * 64 + (f & 3) * 16 + l15, rr = quad * 4 + r;
                sm.c.comb[rt][rr][col] = f2bf(acc[f][r] + bf2f(sm.c.comb[rt][rr][col]));
            }
        #pragma unroll
        for (int f = 8; f < 12; ++f)
            #pragma unroll
            for (int r = 0; r < 4; ++r) {
                int hh = (f & 3) * 16 + l15, kk = rt * 16 + quad * 4 + r;
                sm.c.vsep[hh][kk] = f2bf(acc[f][r] + bf2f(sm.c.vsep[hh][kk]));
            }
    }
    __syncthreads();

    // ---- emission ----
    int b = m0 >> 12, t0 = m0 & 4095;
    int t016 = t0 >> 4, kt32 = t0 >> 5;
    {   // qb: 32 rows x 64 cols
        int row = tid >> 3, ch = tid & 7;
        s16x8 v = *(const s16x8*)&sm.c.comb[row >> 4][row & 15][64 + ch * 8];
        *(s16x8*)&qb[(size_t)(m0 + row) * 64 + ch * 8] = v;
    }
    {   // kfrag: wave task (kt = w&1, ks = w>>1)
        int kt = w & 1, ks = w >> 1;
        s16x8 v = *(const s16x8*)&sm.c.comb[kt][l15][ks * 32 + quad * 8];
        *(s16x8*)&kfrag[(size_t)(((b * 256 + t016 + kt) * 2 + ks) * 64 + lane) * 8] = v;
    }
    {   // vfrag: wave task nt = w
        int nt = w;
        s16x8 v = *(const s16x8*)&sm.c.vsep[nt * 16 + l15][quad * 8];
        *(s16x8*)&vfrag[(size_t)(((b * 128 + kt32) * 4 + nt) * 64 + lane) * 8] = v;
    }
}

// ---------------------------------------------------------------------------
// Kernel 3: flash partials, S^T form, fixed m=0 softmax. Bias tile staged
// coalesced into LDS once per block (16 q-rows x 256 keys fp32); k-loop is
// barrier-free. Block = 4 waves = 4 batches. grid (256 qt, 16 chunk).
// po slot (chunk_off(qt)+c)*4+b : 16x64 O + 16 l, bf16 (1040 shorts).
// ---------------------------------------------------------------------------
#define LOADK(AK, k0) do {                                                    \
    int _kt16 = (k0) >> 4;                                                    \
    _Pragma("unroll")                                                         \
    for (int _n = 0; _n < 2; ++_n) {                                          \
        const short* _kp = kfb + (size_t)((_kt16 + _n) * 2) * 512 + lane * 8; \
        AK[_n * 2]     = *(const s16x8*)_kp;                                  \
        AK[_n * 2 + 1] = *(const s16x8*)(_kp + 512);                          \
    }                                                                         \
} while (0)

#define COMPUTEK(AK, k0) do {                                                 \
    int _kt32 = (k0) >> 5;                                                    \
    int _kl = (k0) - kstart;                                                  \
    s16x8 _bv[4];                                                             \
    _Pragma("unroll")                                                         \
    for (int _n = 0; _n < 4; ++_n)                                            \
        _bv[_n] = *(const s16x8*)(vfb + (size_t)(_kt32 * 4 + _n) * 512 + lane * 8); \
    f32x4 _aS[2];                                                             \
    _Pragma("unroll")                                                         \
    for (int _n = 0; _n < 2; ++_n) {                                          \
        _aS[_n] = (f32x4){0.f, 0.f, 0.f, 0.f};                                \
        _aS[_n] = __builtin_amdgcn_mfma_f32_16x16x32_bf16(AK[_n*2],   aq0, _aS[_n], 0, 0, 0); \
        _aS[_n] = __builtin_amdgcn_mfma_f32_16x16x32_bf16(AK[_n*2+1], aq1, _aS[_n], 0, 0, 0); \
    }                                                                         \
    _Pragma("unroll")                                                         \
    for (int _n = 0; _n < 2; ++_n) {                                          \
        f32x4 _vb = *(const f32x4*)&blds[l15][_kl + _n * 16 + quad * 4];      \
        float _sv[4];                                                         \
        _Pragma("unroll")                                                     \
        for (int _r = 0; _r < 4; ++_r) {                                      \
            _sv[_r] = _aS[_n][_r] + _vb[_r];                                  \
            if (mask_on && ((k0) + _n * 16 + quad * 4 + _r > strip0 + l15))   \
                _sv[_r] = -__builtin_inff();                                  \
            float _p = __expf(_sv[_r]);                                       \
            _sv[_r] = _p;                                                     \
            l_sum += _p;                                                      \
        }                                                                     \
        u32x2 _d;                                                             \
        _d[0] = pack2(_sv[0], _sv[1]);                                        \
        _d[1] = pack2(_sv[2], _sv[3]);                                        \
        *(u32x2*)&plds[w][l15][_n * 16 + quad * 4] = _d;                      \
    }                                                                         \
    s16x8 _ap = *(const s16x8*)&plds[w][l15][quad * 8];                       \
    _Pragma("unroll")                                                         \
    for (int _n = 0; _n < 4; ++_n)                                            \
        accO[_n] = __builtin_amdgcn_mfma_f32_16x16x32_bf16(_ap, _bv[_n], accO[_n], 0, 0, 0); \
} while (0)

__global__ __launch_bounds__(256, 4) void flash_part(
    const short* __restrict__ qb, const short* __restrict__ kfrag,
    const short* __restrict__ vfrag, const float* __restrict__ bias,
    short* __restrict__ po)
{
    int qt = blockIdx.x, c = blockIdx.y;
    if (c > (qt >> 4)) return;                    // block-uniform early exit
    int q0 = qt * 16;
    int kstart = c * CK;
    int kend = min(kstart + CK, q0 + 16);

    __shared__ __align__(16) float blds[16][260]; // bias tile fp32, pad 260
    __shared__ __align__(16) short plds[4][16][40];

    int w = threadIdx.x >> 6, lane = threadIdx.x & 63;  // w = batch
    int b = w;
    int l15 = lane & 15, quad = lane >> 4;
    int strip0 = q0;

    // ---- stage bias: 4 passes, lanes along keys (1 KB contiguous/inst) ----
    #pragma unroll
    for (int p = 0; p < 4; ++p)
        *(f32x4*)&blds[p * 4 + w][lane * 4] =
            *(const f32x4*)&bias[(size_t)(q0 + p * 4 + w) * T_DIM + kstart + lane * 4];

    const short* qrow = qb + (size_t)(b * T_DIM + strip0 + l15) * 64;
    s16x8 aq0 = *(const s16x8*)(qrow + quad * 8);
    s16x8 aq1 = *(const s16x8*)(qrow + 32 + quad * 8);

    float l_sum = 0.f;
    f32x4 accO[4];
    #pragma unroll
    for (int nt = 0; nt < 4; ++nt) accO[nt] = (f32x4){0.f, 0.f, 0.f, 0.f};

    const short* kfb = kfrag + (size_t)b * 256 * 2 * 512;
    const short* vfb = vfrag + (size_t)b * 128 * 4 * 512;
    bool mask_on = (kend > strip0);               // only diagonal chunk masks

    __syncthreads();                              // bias staged

    s16x8 akA[4], akB[4];
    int k0 = kstart;
    LOADK(akA, k0);
    while (true) {
        int k1 = k0 + 32;
        bool more = (k1 < kend);
        if (more) LOADK(akB, k1);
        COMPUTEK(akA, k0);
        if (!more) break;
        k0 = k1; k1 = k0 + 32;
        bool more2 = (k1 < kend);
        if (more2) LOADK(akA, k1);
        COMPUTEK(akB, k0);
        if (!more2) break;
        k0 = k1;
    }

    l_sum += __shfl_xor(l_sum, 16, 64);
    l_sum += __shfl_xor(l_sum, 32, 64);

    short* base = po + (size_t)((chunk_off(qt) + c) * 4 + b) * 1040;
    #pragma unroll
    for (int nt = 0; nt < 4; ++nt)
        #pragma unroll
        for (int r = 0; r < 4; ++r)
            base[(quad * 4 + r) * 64 + nt * 16 + l15] = f2bf(accO[nt][r]);
    if (quad == 0) base[1024 + l15] = f2bf(l_sum);
}

// ---------------------------------------------------------------------------
// Kernel 4: reduce partials + normalize. 1024 x 256.
// ---------------------------------------------------------------------------
__global__ __launch_bounds__(256) void flash_reduce(
    const short* __restrict__ po, float* __restrict__ out)
{
    int idx = blockIdx.x * 256 + threadIdx.x;
    int row = idx >> 4, c4 = idx & 15;
    int b = row >> 12, t = row & 4095;
    int qt = t >> 4, rloc = t & 15;
    int nc = (t >> 8) + 1;
    int off = chunk_off(qt);
    float o0 = 0.f, o1 = 0.f, o2 = 0.f, o3 = 0.f, l = 0.f;
    #pragma unroll 1
    for (int cc = 0; cc < nc; ++cc) {
        const short* base = po + (size_t)((off + cc) * 4 + b) * 1040;
        const short* p = &base[rloc * 64 + c4 * 4];
        o0 += bf2f(p[0]); o1 += bf2f(p[1]); o2 += bf2f(p[2]); o3 += bf2f(p[3]);
        l += bf2f(base[1024 + rloc]);
    }
    float inv = 1.0f / l;
    f32x4 res = (f32x4){o0 * inv, o1 * inv, o2 * inv, o3 * inv};
    *(f32x4*)&out[(size_t)row * 64 + c4 * 4] = res;
}

// ---------------------------------------------------------------------------
extern "C" void kernel_launch(void* const* d_in, const int* in_sizes, int n_in,
                              void* d_out, int out_size, void* d_ws, size_t ws_size,
                              hipStream_t stream) {
    (void)in_sizes; (void)n_in; (void)out_size; (void)ws_size;
    const float* x    = (const float*)d_in[0];
    const float* bias = (const float*)d_in[1];
    const float* wk   = (const float*)d_in[2];
    const float* wq   = (const float*)d_in[3];
    const float* wv   = (const float*)d_in[4];
    float* out = (float*)d_out;

    short* wfrag = (short*)d_ws;                       // 196608
    short* qb    = wfrag + 196608;                     // 1048576 each
    short* kfrag = qb + 1048576;
    short* vfrag = kfrag + 1048576;
    short* po    = vfrag + 1048576;                    // 2176*4*1040 = 9052160

    prep_frag<<<dim3(32, 3), dim3(256), 0, stream>>>(wk, wq, wv, wfrag);
    proj_fused<<<dim3(512), dim3(256), 0, stream>>>(x, wfrag, qb, kfrag, vfrag);
    flash_part<<<dim3(256, 16), dim3(256), 0, stream>>>(qb, kfrag, vfrag, bias, po);
    flash_reduce<<<dim3(1024), dim3(256), 0, stream>>>(po, out);
}

// Round 9
// 196.026 us; speedup vs baseline: 1.5635x; 1.0331x over previous
//
#include <hip/hip_runtime.h>
#include <hip/hip_bf16.h>

// B=4, T=4096, C=1024, H=64 causal attention w/ RPE bias.
// Round 9: proj_fused was latency-bound (MfmaUtil 4.7%, occ 19%, 2 blk/CU,
// unroll-1 K-loop serializing 12 L2 wfrag loads behind MFMAs). Fix: explicit
// A/B double-buffer of wfrag fragments, first prefetch issued before the
// staging barrier. reduce: 16B loads. flash unchanged (now < proj).

#define T_DIM 4096
#define C_DIM 1024
#define CK    256          // flash key-chunk (keys per po partial)

typedef __attribute__((ext_vector_type(8))) short s16x8;
typedef __attribute__((ext_vector_type(4))) float f32x4;
typedef __attribute__((ext_vector_type(2))) unsigned int u32x2;

__device__ __forceinline__ short f2bf(float f) {
    unsigned u = __builtin_bit_cast(unsigned, f);
    u += 0x7FFFu + ((u >> 16) & 1u);
    return (short)(u >> 16);
}
__device__ __forceinline__ unsigned pack2(float a, float b) {
    unsigned ua = __builtin_bit_cast(unsigned, a);
    unsigned ub = __builtin_bit_cast(unsigned, b);
    ua += 0x7FFFu + ((ua >> 16) & 1u);
    ub += 0x7FFFu + ((ub >> 16) & 1u);
    return __builtin_amdgcn_perm(ub, ua, 0x07060302u);
}
__device__ __forceinline__ float bf2f(short s) {
    unsigned u = ((unsigned)(unsigned short)s) << 16;
    return __builtin_bit_cast(float, u);
}
// prefix of active 256-key chunks before 16-q-strip qt: nchunks(j)=j/16+1
__device__ __forceinline__ int chunk_off(int qt) {
    int g = qt >> 4, r = qt & 15;
    return qt + 8 * g * (g - 1) + r * g;
}

// ---------------------------------------------------------------------------
// Kernel 1: weights -> B-fragment order: wfrag[ksAll][mat][nt][lane][8] bf16.
// w_q scaled by 0.125. grid (32, 3) x 256.
// ---------------------------------------------------------------------------
__global__ __launch_bounds__(256) void prep_frag(
    const float* __restrict__ wk, const float* __restrict__ wq,
    const float* __restrict__ wv, short* __restrict__ wfrag)
{
    int ksAll = blockIdx.x, mat = blockIdx.y;
    const float* w = (mat == 0) ? wk : ((mat == 1) ? wq : wv);
    float sc = (mat == 1) ? 0.125f : 1.0f;
    int nt = threadIdx.x >> 6, lane = threadIdx.x & 63;
    int quad = lane >> 4, l15 = lane & 15;
    int h = nt * 16 + l15;
    int cb = ksAll * 32 + quad * 8;
    s16x8 v;
    #pragma unroll
    for (int j = 0; j < 8; ++j) v[j] = f2bf(w[(cb + j) * 64 + h] * sc);
    *(s16x8*)&wfrag[((ksAll * 12 + mat * 4 + nt) * 64 + lane) * 8] = v;
}

// ---------------------------------------------------------------------------
// Kernel 2: fused projection, 32 rows/block, x staged coalesced into LDS,
// wfrag B-fragments double-buffered in registers (L2-latency hiding).
// grid 512 x 256 (4 waves = 2 row-tiles x 2 C-halves).
// ---------------------------------------------------------------------------
union ProjSmem {
    short xs[32][1032];                 // staged x rows (bf16); 1032 pad -> 2-way banks
    struct {
        short comb[2][16][136];         // K cols 0..63, Q cols 64..127
        short vsep[64][40];             // V transposed [h][key 0..31 +pad]
    } c;
};

__global__ __launch_bounds__(256, 2) void proj_fused(
    const float* __restrict__ x, const short* __restrict__ wfrag,
    short* __restrict__ qb, short* __restrict__ kfrag, short* __restrict__ vfrag)
{
    __shared__ __align__(16) ProjSmem sm;

    int tid = threadIdx.x;
    int w = tid >> 6, lane = tid & 63;
    int rt = w >> 1, h = w & 1;
    int l15 = lane & 15, quad = lane >> 4;
    int m0 = blockIdx.x * 32;

    // ---- prefetch wfrag set for ks=0 BEFORE staging (flies during stage) ----
    s16x8 fA[12], fB[12];
    {
        const s16x8* fb = (const s16x8*)&wfrag[((size_t)(h * 16) * 12 * 64 + lane) * 8];
        #pragma unroll
        for (int f = 0; f < 12; ++f) fA[f] = fb[f * 64];
    }

    // ---- stage x: 32 passes, each = one full row, lanes along C ----
    #pragma unroll 8
    for (int p = 0; p < 32; ++p) {
        f32x4 v = *(const f32x4*)&x[(size_t)(m0 + p) * C_DIM + tid * 4];
        u32x2 d;
        d[0] = pack2(v[0], v[1]);
        d[1] = pack2(v[2], v[3]);
        *(u32x2*)&sm.xs[p][tid * 4] = d;
    }
    __syncthreads();

    // ---- MFMA with wfrag double-buffer: wave (rt,h), ksAll = h*16+ks ----
    f32x4 acc[12];
    #pragma unroll
    for (int i = 0; i < 12; ++i) acc[i] = (f32x4){0.f, 0.f, 0.f, 0.f};

    #pragma unroll 1
    for (int ks = 0; ks < 16; ks += 2) {
        {   // prefetch ks+1 into fB
            const s16x8* fb = (const s16x8*)&wfrag[((size_t)(h * 16 + ks + 1) * 12 * 64 + lane) * 8];
            #pragma unroll
            for (int f = 0; f < 12; ++f) fB[f] = fb[f * 64];
        }
        s16x8 af = *(const s16x8*)&sm.xs[rt * 16 + l15][(h * 16 + ks) * 32 + quad * 8];
        #pragma unroll
        for (int f = 0; f < 12; ++f)
            acc[f] = __builtin_amdgcn_mfma_f32_16x16x32_bf16(af, fA[f], acc[f], 0, 0, 0);
        if (ks + 2 < 16) {  // prefetch ks+2 into fA
            const s16x8* fb = (const s16x8*)&wfrag[((size_t)(h * 16 + ks + 2) * 12 * 64 + lane) * 8];
            #pragma unroll
            for (int f = 0; f < 12; ++f) fA[f] = fb[f * 64];
        }
        s16x8 af2 = *(const s16x8*)&sm.xs[rt * 16 + l15][(h * 16 + ks + 1) * 32 + quad * 8];
        #pragma unroll
        for (int f = 0; f < 12; ++f)
            acc[f] = __builtin_amdgcn_mfma_f32_16x16x32_bf16(af2, fB[f], acc[f], 0, 0, 0);
    }
    __syncthreads();   // all waves done reading xs; union -> combine buffers

    // ---- combine: h=1 parks, h=0 adds ----
    if (h == 1) {
        #pragma unroll
        for (int f = 0; f < 8; ++f)
            #pragma unroll
            for (int r = 0; r < 4; ++r)
                sm.c.comb[rt][quad * 4 + r][(f >> 2) * 64 + (f & 3) * 16 + l15] = f2bf(acc[f][r]);
        #pragma unroll
        for (int f = 8; f < 12; ++f)
            #pragma unroll
            for (int r = 0; r < 4; ++r)
                sm.c.vsep[(f & 3) * 16 + l15][rt * 16 + quad * 4 + r] = f2bf(acc[f][r]);
    }
    __syncthreads();
    if (h == 0) {
        #pragma unroll
        for (int f = 0; f < 8; ++f)
            #pragma unroll
            for (int r = 0; r < 4; ++r) {
                int col = (f >> 2) * 64 + (f & 3) * 16 + l15, rr = quad * 4 + r;
                sm.c.comb[rt][rr][col] = f2bf(acc[f][r] + bf2f(sm.c.comb[rt][rr][col]));
            }
        #pragma unroll
        for (int f = 8; f < 12; ++f)
            #pragma unroll
            for (int r = 0; r < 4; ++r) {
                int hh = (f & 3) * 16 + l15, kk = rt * 16 + quad * 4 + r;
                sm.c.vsep[hh][kk] = f2bf(acc[f][r] + bf2f(sm.c.vsep[hh][kk]));
            }
    }
    __syncthreads();

    // ---- emission ----
    int b = m0 >> 12, t0 = m0 & 4095;
    int t016 = t0 >> 4, kt32 = t0 >> 5;
    {   // qb: 32 rows x 64 cols
        int row = tid >> 3, ch = tid & 7;
        s16x8 v = *(const s16x8*)&sm.c.comb[row >> 4][row & 15][64 + ch * 8];
        *(s16x8*)&qb[(size_t)(m0 + row) * 64 + ch * 8] = v;
    }
    {   // kfrag: wave task (kt = w&1, ks = w>>1)
        int kt = w & 1, ks = w >> 1;
        s16x8 v = *(const s16x8*)&sm.c.comb[kt][l15][ks * 32 + quad * 8];
        *(s16x8*)&kfrag[(size_t)(((b * 256 + t016 + kt) * 2 + ks) * 64 + lane) * 8] = v;
    }
    {   // vfrag: wave task nt = w
        int nt = w;
        s16x8 v = *(const s16x8*)&sm.c.vsep[nt * 16 + l15][quad * 8];
        *(s16x8*)&vfrag[(size_t)(((b * 128 + kt32) * 4 + nt) * 64 + lane) * 8] = v;
    }
}

// ---------------------------------------------------------------------------
// Kernel 3: flash partials, S^T form, fixed m=0 softmax. Bias tile staged
// coalesced into LDS once per block; k-loop barrier-free. Block = 4 waves =
// 4 batches. grid (256 qt, 16 chunk). po slot: 16x64 O + 16 l bf16.
// ---------------------------------------------------------------------------
#define LOADK(AK, k0) do {                                                    \
    int _kt16 = (k0) >> 4;                                                    \
    _Pragma("unroll")                                                         \
    for (int _n = 0; _n < 2; ++_n) {                                          \
        const short* _kp = kfb + (size_t)((_kt16 + _n) * 2) * 512 + lane * 8; \
        AK[_n * 2]     = *(const s16x8*)_kp;                                  \
        AK[_n * 2 + 1] = *(const s16x8*)(_kp + 512);                          \
    }                                                                         \
} while (0)

#define COMPUTEK(AK, k0) do {                                                 \
    int _kt32 = (k0) >> 5;                                                    \
    int _kl = (k0) - kstart;                                                  \
    s16x8 _bv[4];                                                             \
    _Pragma("unroll")                                                         \
    for (int _n = 0; _n < 4; ++_n)                                            \
        _bv[_n] = *(const s16x8*)(vfb + (size_t)(_kt32 * 4 + _n) * 512 + lane * 8); \
    f32x4 _aS[2];                                                             \
    _Pragma("unroll")                                                         \
    for (int _n = 0; _n < 2; ++_n) {                                          \
        _aS[_n] = (f32x4){0.f, 0.f, 0.f, 0.f};                                \
        _aS[_n] = __builtin_amdgcn_mfma_f32_16x16x32_bf16(AK[_n*2],   aq0, _aS[_n], 0, 0, 0); \
        _aS[_n] = __builtin_amdgcn_mfma_f32_16x16x32_bf16(AK[_n*2+1], aq1, _aS[_n], 0, 0, 0); \
    }                                                                         \
    _Pragma("unroll")                                                         \
    for (int _n = 0; _n < 2; ++_n) {                                          \
        f32x4 _vb = *(const f32x4*)&blds[l15][_kl + _n * 16 + quad * 4];      \
        float _sv[4];                                                         \
        _Pragma("unroll")                                                     \
        for (int _r = 0; _r < 4; ++_r) {                                      \
            _sv[_r] = _aS[_n][_r] + _vb[_r];                                  \
            if (mask_on && ((k0) + _n * 16 + quad * 4 + _r > strip0 + l15))   \
                _sv[_r] = -__builtin_inff();                                  \
            float _p = __expf(_sv[_r]);                                       \
            _sv[_r] = _p;                                                     \
            l_sum += _p;                                                      \
        }                                                                     \
        u32x2 _d;                                                             \
        _d[0] = pack2(_sv[0], _sv[1]);                                        \
        _d[1] = pack2(_sv[2], _sv[3]);                                        \
        *(u32x2*)&plds[w][l15][_n * 16 + quad * 4] = _d;                      \
    }                                                                         \
    s16x8 _ap = *(const s16x8*)&plds[w][l15][quad * 8];                       \
    _Pragma("unroll")                                                         \
    for (int _n = 0; _n < 4; ++_n)                                            \
        accO[_n] = __builtin_amdgcn_mfma_f32_16x16x32_bf16(_ap, _bv[_n], accO[_n], 0, 0, 0); \
} while (0)

__global__ __launch_bounds__(256, 4) void flash_part(
    const short* __restrict__ qb, const short* __restrict__ kfrag,
    const short* __restrict__ vfrag, const float* __restrict__ bias,
    short* __restrict__ po)
{
    int qt = blockIdx.x, c = blockIdx.y;
    if (c > (qt >> 4)) return;                    // block-uniform early exit
    int q0 = qt * 16;
    int kstart = c * CK;
    int kend = min(kstart + CK, q0 + 16);

    __shared__ __align__(16) float blds[16][260]; // bias tile fp32, pad 260
    __shared__ __align__(16) short plds[4][16][40];

    int w = threadIdx.x >> 6, lane = threadIdx.x & 63;  // w = batch
    int b = w;
    int l15 = lane & 15, quad = lane >> 4;
    int strip0 = q0;

    // ---- stage bias: 4 passes, lanes along keys (1 KB contiguous/inst) ----
    #pragma unroll
    for (int p = 0; p < 4; ++p)
        *(f32x4*)&blds[p * 4 + w][lane * 4] =
            *(const f32x4*)&bias[(size_t)(q0 + p * 4 + w) * T_DIM + kstart + lane * 4];

    const short* qrow = qb + (size_t)(b * T_DIM + strip0 + l15) * 64;
    s16x8 aq0 = *(const s16x8*)(qrow + quad * 8);
    s16x8 aq1 = *(const s16x8*)(qrow + 32 + quad * 8);

    float l_sum = 0.f;
    f32x4 accO[4];
    #pragma unroll
    for (int nt = 0; nt < 4; ++nt) accO[nt] = (f32x4){0.f, 0.f, 0.f, 0.f};

    const short* kfb = kfrag + (size_t)b * 256 * 2 * 512;
    const short* vfb = vfrag + (size_t)b * 128 * 4 * 512;
    bool mask_on = (kend > strip0);               // only diagonal chunk masks

    __syncthreads();                              // bias staged

    s16x8 akA[4], akB[4];
    int k0 = kstart;
    LOADK(akA, k0);
    while (true) {
        int k1 = k0 + 32;
        bool more = (k1 < kend);
        if (more) LOADK(akB, k1);
        COMPUTEK(akA, k0);
        if (!more) break;
        k0 = k1; k1 = k0 + 32;
        bool more2 = (k1 < kend);
        if (more2) LOADK(akA, k1);
        COMPUTEK(akB, k0);
        if (!more2) break;
        k0 = k1;
    }

    l_sum += __shfl_xor(l_sum, 16, 64);
    l_sum += __shfl_xor(l_sum, 32, 64);

    short* base = po + (size_t)((chunk_off(qt) + c) * 4 + b) * 1040;
    #pragma unroll
    for (int nt = 0; nt < 4; ++nt)
        #pragma unroll
        for (int r = 0; r < 4; ++r)
            base[(quad * 4 + r) * 64 + nt * 16 + l15] = f2bf(accO[nt][r]);
    if (quad == 0) base[1024 + l15] = f2bf(l_sum);
}

// ---------------------------------------------------------------------------
// Kernel 4: reduce partials + normalize. 512 x 256, 16B loads (8 thr/row).
// ---------------------------------------------------------------------------
__global__ __launch_bounds__(256) void flash_reduce(
    const short* __restrict__ po, float* __restrict__ out)
{
    int idx = blockIdx.x * 256 + threadIdx.x;     // 131072 = 16384 rows x 8
    int row = idx >> 3, c8 = idx & 7;
    int b = row >> 12, t = row & 4095;
    int qt = t >> 4, rloc = t & 15;
    int nc = (t >> 8) + 1;
    int off = chunk_off(qt);
    float o[8];
    #pragma unroll
    for (int j = 0; j < 8; ++j) o[j] = 0.f;
    float l = 0.f;
    #pragma unroll 1
    for (int cc = 0; cc < nc; ++cc) {
        const short* base = po + (size_t)((off + cc) * 4 + b) * 1040;
        s16x8 v = *(const s16x8*)&base[rloc * 64 + c8 * 8];
        #pragma unroll
        for (int j = 0; j < 8; ++j) o[j] += bf2f(v[j]);
        l += bf2f(base[1024 + rloc]);
    }
    float inv = 1.0f / l;
    f32x4 r0 = (f32x4){o[0] * inv, o[1] * inv, o[2] * inv, o[3] * inv};
    f32x4 r1 = (f32x4){o[4] * inv, o[5] * inv, o[6] * inv, o[7] * inv};
    float* op = &out[(size_t)row * 64 + c8 * 8];
    *(f32x4*)op = r0;
    *(f32x4*)(op + 4) = r1;
}

// ---------------------------------------------------------------------------
extern "C" void kernel_launch(void* const* d_in, const int* in_sizes, int n_in,
                              void* d_out, int out_size, void* d_ws, size_t ws_size,
                              hipStream_t stream) {
    (void)in_sizes; (void)n_in; (void)out_size; (void)ws_size;
    const float* x    = (const float*)d_in[0];
    const float* bias = (const float*)d_in[1];
    const float* wk   = (const float*)d_in[2];
    const float* wq   = (const float*)d_in[3];
    const float* wv   = (const float*)d_in[4];
    float* out = (float*)d_out;

    short* wfrag = (short*)d_ws;                       // 196608
    short* qb    = wfrag + 196608;                     // 1048576 each
    short* kfrag = qb + 1048576;
    short* vfrag = kfrag + 1048576;
    short* po    = vfrag + 1048576;                    // 2176*4*1040 = 9052160

    prep_frag<<<dim3(32, 3), dim3(256), 0, stream>>>(wk, wq, wv, wfrag);
    proj_fused<<<dim3(512), dim3(256), 0, stream>>>(x, wfrag, qb, kfrag, vfrag);
    flash_part<<<dim3(256, 16), dim3(256), 0, stream>>>(qb, kfrag, vfrag, bias, po);
    flash_reduce<<<dim3(512), dim3(256), 0, stream>>>(po, out);
}